// Round 7
// baseline (334.784 us; speedup 1.0000x reference)
//
#include <hip/hip_runtime.h>

// ConvLSTM1D fused scan for MI355X — f32 I/O, bf16 MFMA.
// Round 13: HALVE THE HALO with one mid-scan handshake. Rounds 7/11/12 proved
// occupancy pushes don't pay (wall tracks slot-step work at ~47% VALU duty,
// 2 blocks/CU); round 8 proved per-step handshakes are fatal. This keeps the
// round-9 structure (LTILE=64, 512 blocks, reg-held prepermuted B-tables)
// but at t=25 each block publishes h^25/c^25 rows 0..24 to its left neighbor
// (4.8 KB, one release-flag), so BOTH phases run depth-24 halos:
// slot-steps 348 -> 264 per block (x0.76 work). Reversed tile mapping makes
// producers lower-blockIdx than consumers (progress even if not co-resident);
// publish happens BEFORE consume so there is no chained stall.
// Also: prep kernel 64 -> 512 threads (it was one latency-bound wave).
// Halo-tile trick per phase: recurrent conv reads h[j+1] only, so a right
// halo of depth (phase length) that shrinks 1 row/step keeps every block's
// scan segment fully independent between handshakes.

#define TT 50
#define HD 25      // phase length = halo depth
#define LTILE 64
#define ROWS 97    // 6 slots x 16 + 1 read-halo row (row 96 stays 0)
#define HSTR 40    // h row stride (shorts); mult of 8 -> 16B-aligned ds_read_b128

typedef __attribute__((ext_vector_type(8))) short short8;
typedef __attribute__((ext_vector_type(4))) float floatx4;

// Prepermuted bf16 weight fragment tables: index [n*64 + lane].
__device__ short8 g_tw0[512];   // rec_kernel tap rows 0..31  (k = q*8+j)
__device__ short8 g_tw1[512];   // rec_kernel tap rows 32..63
__device__ short8 g_txw[512];   // x-conv taps (k rows 0..15) + bias row 16

// Mid-scan exchange buffers: h^25 / c^25 rows 0..24 of each block.
__device__ unsigned g_xh[512 * 400];   // 25 rows x 16 dwords (2 bf16 each)
__device__ float    g_xc[512 * 800];   // 25 rows x 32 f32
__device__ int      g_flag[512];

__device__ __forceinline__ unsigned short f2b_rne(float f) {
  union { float f; unsigned u; } v; v.f = f;
  unsigned r = v.u + 0x7FFFu + ((v.u >> 16) & 1u);
  return (unsigned short)(r >> 16);
}
__device__ __forceinline__ unsigned short f2b_trunc(float f) {
  union { float f; unsigned u; } v; v.f = f;
  return (unsigned short)(v.u >> 16);
}
__device__ __forceinline__ float hsig(float x) {
  return __builtin_amdgcn_fmed3f(__builtin_fmaf(0.2f, x, 0.5f), 0.0f, 1.0f);
}
__device__ __forceinline__ float ftanh(float x) {
  float e = __expf(2.0f * x);
  return 1.0f - 2.0f * __builtin_amdgcn_rcpf(e + 1.0f);
}

// ---- prep: fragment tables (512 threads: one per (n,lane)) + zero ws/flags.
__global__ void prep(const float* __restrict__ ks,
                     const float* __restrict__ rks,
                     const float* __restrict__ bs,
                     float* __restrict__ ws) {
  const int tid  = threadIdx.x;        // 0..511
  const int n    = tid >> 6;
  const int lane = tid & 63;
  const int q    = lane >> 4;
  const int f0   = lane & 15;
  if (tid < 32) ws[tid] = 0.0f;
  g_flag[tid] = 0;

  // Gate-pair permutation: tile n = 2g+p, col f0  <->  oc = g*32 + 2*f0 + p
  const int oc = (n >> 1) * 32 + 2 * f0 + (n & 1);
  short8 th;
#pragma unroll
  for (int j = 0; j < 8; ++j)
    th[j] = (short)f2b_rne(rks[(q * 8 + j) * 128 + oc]);
  g_tw0[n * 64 + lane] = th;
#pragma unroll
  for (int j = 0; j < 8; ++j)
    th[j] = (short)f2b_rne(rks[(32 + q * 8 + j) * 128 + oc]);
  g_tw1[n * 64 + lane] = th;
  short8 tx = {0, 0, 0, 0, 0, 0, 0, 0};
  if (q < 2) {
#pragma unroll
    for (int j = 0; j < 8; ++j)
      tx[j] = (short)f2b_rne(ks[(q * 8 + j) * 128 + oc]);
  } else if (q == 2) {
    tx[0] = (short)f2b_rne(bs[oc]);    // bias row 16 (ax carries 1.0 there)
  }
  g_txw[n * 64 + lane] = tx;
}

__global__ __launch_bounds__(256, 2)
void convlstm_scan(const float* __restrict__ xs,   // x [32][50][2048][8] f32
                   const float* __restrict__ dws,  // dense_w [32768] f32
                   float* __restrict__ acc_out) {  // [32] f32 accumulators
  __shared__ short hbH[2][ROWS * HSTR];   // h (bf16), double-buffered, 15.5 KB

  const int tid  = threadIdx.x;
  const int b    = blockIdx.x >> 4;
  const int pi   = blockIdx.x & 15;    // physical tile slot
  const int tj   = 15 - pi;            // REVERSED: producers get lower blockIdx
  const int j0   = tj << 6;
  const int wave = tid >> 6;
  const int lane = tid & 63;
  const int q    = lane >> 4;
  const int f0   = lane & 15;
  const bool is_pub = (pi < 15);       // consumer pi+1 (tile tj-1) exists
  const bool is_con = (pi >= 1);       // producer pi-1 (tile tj+1) exists

  for (int e = tid; e < ROWS * HSTR; e += 256)   // ints cover both buffers
    ((int*)hbH)[e] = 0;

  // ---- B fragments: coalesced loads from the prepermuted tables.
  short8 Bwh0[8], Bwh1[8], Bxw[8];
#pragma unroll
  for (int n = 0; n < 8; ++n) {
    Bwh0[n] = g_tw0[n * 64 + lane];
    Bwh1[n] = g_tw1[n * 64 + lane];
    Bxw[n]  = g_txw[n * 64 + lane];
  }

  short8 axc = {0, 0, 0, 0, 0, 0, 0, 0};
  if (q == 2) axc[0] = (short)0x3F80;   // bias marker 1.0 at k=16
  const floatx4 zero4 = {0.0f, 0.0f, 0.0f, 0.0f};

  float cst[2][8];   // c-state, MFMA C-layout: [m-slot][p*4 + r]
#pragma unroll
  for (int s = 0; s < 2; ++s)
#pragma unroll
    for (int i = 0; i < 8; ++i) cst[s][i] = 0.0f;

  // ---- initial x prefetch (t=0) for both slots (only q<2 feeds ax)
  floatx4 px0[2], px1[2];
#pragma unroll
  for (int s = 0; s < 2; ++s) {
    px0[s] = zero4; px1[s] = zero4;
    const int jr = (wave + 4 * s) * 16 + f0;
    const int jm = min(j0 + jr, 1023);
    if (q < 2) {
      const float* xp = xs + (size_t)b * TT * (2048 * 8) +
                        (size_t)(2 * jm + q) * 8;
      px0[s] = *(const floatx4*)xp;
      px1[s] = *(const floatx4*)(xp + 4);
    }
  }

  const int maxrows = 1024 - j0;
  float part = 0.0f;                        // fused Dense(1) partial
  __syncthreads();

  for (int t = 0; t < TT; ++t) {
    // ================= mid-scan halo exchange (once, at t=25) =============
    if (t == HD) {
      short* bufH = hbH[HD & 1];            // h^25 lives here (curH for t=25)
      if (is_pub) {
        // h^25 rows 0..24 (bit-exact bf16 pairs from LDS)
        for (int e = tid; e < 400; e += 256) {
          const int row = e >> 4, d = e & 15;
          g_xh[blockIdx.x * 400 + e] = *(const unsigned*)&bufH[row * HSTR + 2 * d];
        }
        // c^25 rows 0..24 from cst[0] of waves 0,1 (exact f32)
        if (wave == 0) {
#pragma unroll
          for (int r = 0; r < 4; ++r)
#pragma unroll
            for (int pp = 0; pp < 2; ++pp)
              g_xc[blockIdx.x * 800 + (q * 4 + r) * 32 + 2 * f0 + pp] = cst[0][pp * 4 + r];
        } else if (wave == 1) {
#pragma unroll
          for (int r = 0; r < 4; ++r)
            if (q * 4 + r <= 8) {           // rows 16..24 only
#pragma unroll
              for (int pp = 0; pp < 2; ++pp)
                g_xc[blockIdx.x * 800 + (16 + q * 4 + r) * 32 + 2 * f0 + pp] = cst[0][pp * 4 + r];
            }
        }
      }
      __threadfence();                      // order my stores before my flag
      __syncthreads();
      if (is_pub && tid == 0)
        __hip_atomic_store(&g_flag[blockIdx.x], 1, __ATOMIC_RELEASE,
                           __HIP_MEMORY_SCOPE_AGENT);
      if (is_con) {
        if (tid == 0) {
          while (__hip_atomic_load(&g_flag[blockIdx.x - 1], __ATOMIC_RELAXED,
                                   __HIP_MEMORY_SCOPE_AGENT) == 0)
            __builtin_amdgcn_s_sleep(2);
        }
        __syncthreads();
        __builtin_amdgcn_fence(__ATOMIC_ACQUIRE, "agent");  // invalidate L1
        // halo h rows 64..88 <- producer rows 0..24
        for (int e = tid; e < 400; e += 256) {
          const int row = e >> 4, d = e & 15;
          *(unsigned*)&bufH[(64 + row) * HSTR + 2 * d] =
              g_xh[(blockIdx.x - 1) * 400 + e];
        }
        // halo c rows 64..88 -> slot 4 (wave0,s1) rows 64..79,
        //                       slot 5 (wave1,s1) rows 80..88
        if (wave == 0) {
#pragma unroll
          for (int r = 0; r < 4; ++r)
#pragma unroll
            for (int pp = 0; pp < 2; ++pp)
              cst[1][pp * 4 + r] = g_xc[(blockIdx.x - 1) * 800 + (q * 4 + r) * 32 + 2 * f0 + pp];
        } else if (wave == 1) {
#pragma unroll
          for (int r = 0; r < 4; ++r)
            if (q * 4 + r <= 8) {
#pragma unroll
              for (int pp = 0; pp < 2; ++pp)
                cst[1][pp * 4 + r] = g_xc[(blockIdx.x - 1) * 800 + (16 + q * 4 + r) * 32 + 2 * f0 + pp];
            }
        }
      }
      __syncthreads();                      // halo LDS writes before body reads
    }
    // ======================================================================

    const short* curH = hbH[t & 1];
    short* nxtH = hbH[(t & 1) ^ 1];
    // phase-local halo: depth 24, shrinks 1 row/step
    int rows = LTILE - 1 + ((t < HD) ? HD : TT) - t;
    if (rows > maxrows) rows = maxrows;
    const int nmt = (rows + 15) >> 4;         // 4..6; slot0 always live
    const int act1 = (wave + 4) < nmt;        // only waves 0,1 ever have slot1
    const int last = (t == TT - 1);
    const int tn = last ? t : t + 1;
    const float* xnext = xs + ((size_t)(b * TT + tn)) * (2048 * 8);

    // 1) Front-load a-frag LDS reads (max read row = 96 = ROWS-1, stays 0).
    short8 a0h[2], a1h[2];
#pragma unroll
    for (int s = 0; s < 2; ++s) {
      if (s == 1 && !act1) continue;
      const int jr = (wave + 4 * s) * 16 + f0;
      a0h[s] = *(const short8*)&curH[jr * HSTR + q * 8];
      a1h[s] = *(const short8*)&curH[(jr + 1) * HSTR + q * 8];
    }

    // 2) Build ax (x_hi) from registers prefetched last step.
    short8 ax[2];
#pragma unroll
    for (int s = 0; s < 2; ++s) {
      ax[s] = axc;
      if (q < 2) {
        floatx4 x0 = px0[s], x1 = px1[s];
#pragma unroll
        for (int jj = 0; jj < 4; ++jj) ax[s][jj] = (short)f2b_trunc(x0[jj]);
#pragma unroll
        for (int jj = 0; jj < 4; ++jj) ax[s][4 + jj] = (short)f2b_trunc(x1[jj]);
      }
    }

    // 3) Issue next-step x prefetch (longest latency, overlaps MFMA below).
#pragma unroll
    for (int s = 0; s < 2; ++s) {
      if (q >= 2) continue;
      const int jr = (wave + 4 * s) * 16 + f0;
      const int jm = min(j0 + jr, 1023);
      const float* xp = xnext + (size_t)(2 * jm + q) * 8;
      px0[s] = *(const floatx4*)xp;
      px1[s] = *(const floatx4*)(xp + 4);
    }

    // 4) Per-slot MFMA + pointwise.
#pragma unroll
    for (int s = 0; s < 2; ++s) {
      if (s == 1 && !act1) continue;
      const int m = wave + 4 * s;

      floatx4 acc[8];
#pragma unroll
      for (int n = 0; n < 8; ++n)
        acc[n] = __builtin_amdgcn_mfma_f32_16x16x32_bf16(ax[s], Bxw[n], zero4, 0, 0, 0);
#pragma unroll
      for (int n = 0; n < 8; ++n)
        acc[n] = __builtin_amdgcn_mfma_f32_16x16x32_bf16(a0h[s], Bwh0[n], acc[n], 0, 0, 0);
#pragma unroll
      for (int n = 0; n < 8; ++n)
        acc[n] = __builtin_amdgcn_mfma_f32_16x16x32_bf16(a1h[s], Bwh1[n], acc[n], 0, 0, 0);

      // Pointwise LSTM. D[m-row = q*4+r][tile n, col f0 -> h-col 2f0 + (n&1)].
      const int jw = m * 16 + q * 4;
#pragma unroll
      for (int r = 0; r < 4; ++r) {
        float hv2[2];
#pragma unroll
        for (int p = 0; p < 2; ++p) {
          float zi = acc[0 + p][r], zf = acc[2 + p][r];
          float zc = acc[4 + p][r], zo = acc[6 + p][r];
          float ig = hsig(zi), fg = hsig(zf), og = hsig(zo);
          float cs = cst[s][p * 4 + r];
          float cn = __builtin_fmaf(fg, cs, ig * ftanh(zc));
          cst[s][p * 4 + r] = cn;
          hv2[p] = og * ftanh(cn);
        }
        if (!last) {
          unsigned pk;
          asm("v_cvt_pk_bf16_f32 %0, %1, %2"
              : "=v"(pk) : "v"(hv2[0]), "v"(hv2[1]));
          *(unsigned*)&nxtH[(jw + r) * HSTR + 2 * f0] = pk;
        } else {
          // t=49: nmt=4, s=0 only; rows jw+r cover exactly [0,64).
          const int di = (j0 + jw + r) * 32 + 2 * f0;
          part = __builtin_fmaf(hv2[0], dws[di],
                 __builtin_fmaf(hv2[1], dws[di + 1], part));
        }
      }
    }
    __syncthreads();
  }

  // ---- reduce fused-dense partials
#pragma unroll
  for (int off = 32; off > 0; off >>= 1) part += __shfl_down(part, off);
  if (lane == 0) atomicAdd(&acc_out[b], part);
}

__global__ void finalize(const float* __restrict__ ws,
                         const float* __restrict__ db,
                         float* __restrict__ out) {
  int i = threadIdx.x;
  if (i < 32) out[i] = ws[i] + db[0];
}

extern "C" void kernel_launch(void* const* d_in, const int* in_sizes, int n_in,
                              void* d_out, int out_size, void* d_ws, size_t ws_size,
                              hipStream_t stream) {
  const float* x  = (const float*)d_in[0];
  const float* k  = (const float*)d_in[1];
  const float* rk = (const float*)d_in[2];
  const float* bi = (const float*)d_in[3];
  const float* dw = (const float*)d_in[4];
  const float* db = (const float*)d_in[5];
  float* ws = (float*)d_ws;
  float* out = (float*)d_out;

  hipLaunchKernelGGL(prep, dim3(1), dim3(512), 0, stream, k, rk, bi, ws);
  hipLaunchKernelGGL(convlstm_scan, dim3(512), dim3(256), 0, stream,
                     x, dw, ws);
  hipLaunchKernelGGL(finalize, dim3(1), dim3(64), 0, stream, ws, db, out);
}

// Round 8
// 250.660 us; speedup vs baseline: 1.3356x; 1.3356x over previous
//
#include <hip/hip_runtime.h>

// ConvLSTM1D fused scan for MI355X — f32 I/O, bf16 MFMA.
// Round 14: r10-redux WITHOUT the spill. 512-thread blocks, ONE m-slot per
// wave (wave w owns rows [16w,16w+16)): halves the per-step block critical
// path (the barrier waits for the slowest wave, which in r9 ran 2 slots =
// ~1100cyc of pointwise while siblings idled). Total work identical to r9.
// r10's regression was solely launch_bounds(512,4)'s 128-VGPR cap spilling
// the 96-reg B-fragment file to scratch (WRITE_SIZE 37MB); here
// launch_bounds(512,2) caps at 256 -> ~150 live regs fit, no spill,
// 1 block/CU = 8 waves/CU (same concurrency as r9, half the critpath).
// Also: ax built with v_perm_b32 (2 f32 -> packed bf16-hi pair per op,
// bit-identical to f2b_trunc) replacing ~12 shift/pack ops with 4.
// Cross-block communication is permanently banned (r8: ~20us/link, r13:
// ~100us one-shot agent-fence cost — both measured fatal).
// Halo-tile trick: block owns j-range [j0, j0+64); recurrent conv reads h[j+1]
// only, so a right halo that starts at +49 rows and shrinks by 1 per step makes
// every block's 50-step scan fully independent (no grid sync).

#define TT 50
#define LTILE 64
#define ROWS 129   // 64 owned + 49 halo + 1 read-halo row (row 128 stays 0)
#define HSTR 40    // h row stride (shorts); mult of 8 -> 16B-aligned ds_read_b128

typedef __attribute__((ext_vector_type(8))) short short8;
typedef __attribute__((ext_vector_type(4))) float floatx4;

// Prepermuted bf16 weight fragment tables: index [n*64 + lane].
__device__ short8 g_tw0[512];   // rec_kernel tap rows 0..31  (k = q*8+j)
__device__ short8 g_tw1[512];   // rec_kernel tap rows 32..63
__device__ short8 g_txw[512];   // x-conv taps (k rows 0..15) + bias row 16

__device__ __forceinline__ unsigned short f2b_rne(float f) {
  union { float f; unsigned u; } v; v.f = f;
  unsigned r = v.u + 0x7FFFu + ((v.u >> 16) & 1u);
  return (unsigned short)(r >> 16);
}
__device__ __forceinline__ float hsig(float x) {
  return __builtin_amdgcn_fmed3f(__builtin_fmaf(0.2f, x, 0.5f), 0.0f, 1.0f);
}
__device__ __forceinline__ float ftanh(float x) {
  float e = __expf(2.0f * x);
  return 1.0f - 2.0f * __builtin_amdgcn_rcpf(e + 1.0f);
}

// ---- prep: fragment tables (512 threads: one per (n,lane)) + zero ws.
__global__ void prep(const float* __restrict__ ks,
                     const float* __restrict__ rks,
                     const float* __restrict__ bs,
                     float* __restrict__ ws) {
  const int tid  = threadIdx.x;        // 0..511
  const int n    = tid >> 6;
  const int lane = tid & 63;
  const int q    = lane >> 4;
  const int f0   = lane & 15;
  if (tid < 32) ws[tid] = 0.0f;

  // Gate-pair permutation: tile n = 2g+p, col f0  <->  oc = g*32 + 2*f0 + p
  const int oc = (n >> 1) * 32 + 2 * f0 + (n & 1);
  short8 th;
#pragma unroll
  for (int j = 0; j < 8; ++j)
    th[j] = (short)f2b_rne(rks[(q * 8 + j) * 128 + oc]);
  g_tw0[n * 64 + lane] = th;
#pragma unroll
  for (int j = 0; j < 8; ++j)
    th[j] = (short)f2b_rne(rks[(32 + q * 8 + j) * 128 + oc]);
  g_tw1[n * 64 + lane] = th;
  // x-conv B: k rows 0..7 = tap0, 8..15 = tap1 (paired with x_hi),
  // row 16 = bias (ax carries 1.0 there), rows 17..31 = 0.
  short8 tx = {0, 0, 0, 0, 0, 0, 0, 0};
  if (q < 2) {
#pragma unroll
    for (int j = 0; j < 8; ++j)
      tx[j] = (short)f2b_rne(ks[(q * 8 + j) * 128 + oc]);
  } else if (q == 2) {
    tx[0] = (short)f2b_rne(bs[oc]);
  }
  g_txw[n * 64 + lane] = tx;
}

__global__ __launch_bounds__(512, 2)
void convlstm_scan(const float* __restrict__ xs,   // x [32][50][2048][8] f32
                   const float* __restrict__ dws,  // dense_w [32768] f32
                   float* __restrict__ acc_out) {  // [32] f32 accumulators
  __shared__ short hbH[2][ROWS * HSTR];   // h (bf16), double-buffered, 20.6 KB

  const int tid  = threadIdx.x;
  const int b    = blockIdx.x >> 4;
  const int j0   = (blockIdx.x & 15) * LTILE;
  const int wave = tid >> 6;           // = the ONE m-slot owned by this wave
  const int lane = tid & 63;
  const int q    = lane >> 4;
  const int f0   = lane & 15;

  for (int e = tid; e < ROWS * HSTR; e += 512)   // ints cover both buffers
    ((int*)hbH)[e] = 0;

  // ---- B fragments: coalesced loads from the prepermuted tables.
  // tile n = 2g+p, col f0  <->  oc = g*32 + 2*f0 + p  => lane f0's two
  // outputs per row are adjacent h-cols 2f0, 2f0+1 (packed b32 store).
  short8 Bwh0[8], Bwh1[8], Bxw[8];
#pragma unroll
  for (int n = 0; n < 8; ++n) {
    Bwh0[n] = g_tw0[n * 64 + lane];
    Bwh1[n] = g_tw1[n * 64 + lane];
    Bxw[n]  = g_txw[n * 64 + lane];
  }

  // ax constant part: lane (q=2, elem 0) = bf16 1.0 (bias marker), else 0.
  short8 axc = {0, 0, 0, 0, 0, 0, 0, 0};
  if (q == 2) axc[0] = (short)0x3F80;

  const floatx4 zero4 = {0.0f, 0.0f, 0.0f, 0.0f};

  float cst[8];   // c-state, MFMA C-layout: [p*4 + r]
#pragma unroll
  for (int i = 0; i < 8; ++i) cst[i] = 0.0f;

  // ---- per-wave fixed row; initial x prefetch (t=0); only q<2 feeds ax
  const int jr = wave * 16 + f0;            // row in window, < 128
  const int jm = min(j0 + jr, 1023);        // clamp (safety; see analysis)
  const float* xbase = xs + (size_t)b * TT * (2048 * 8);
  floatx4 px0 = zero4, px1 = zero4;
  if (q < 2) {
    const float* xp = xbase + (size_t)(2 * jm + q) * 8;
    px0 = *(const floatx4*)xp;
    px1 = *(const floatx4*)(xp + 4);
  }

  const int maxrows = 1024 - j0;
  float part = 0.0f;                        // fused Dense(1) partial
  __syncthreads();

  for (int t = 0; t < TT; ++t) {
    const short* curH = hbH[t & 1];
    short* nxtH = hbH[(t & 1) ^ 1];
    int rows = LTILE + (TT - 1) - t;          // halo shrinks 1/step
    if (rows > maxrows) rows = maxrows;
    const int nmt = (rows + 15) >> 4;         // 4..8 live m-slots
    const int last = (t == TT - 1);

    if (wave < nmt) {                         // wave-uniform activity guard
      // 1) a-frag LDS reads (max read row = 128 = ROWS-1, stays 0).
      short8 a0h = *(const short8*)&curH[jr * HSTR + q * 8];
      short8 a1h = *(const short8*)&curH[(jr + 1) * HSTR + q * 8];

      // 2) ax (x_hi) from regs prefetched last step, via v_perm byte-pick:
      // dword = (hi16(pxA) << 16) | hi16(pxB)  == pair of f2b_trunc.
      short8 ax = axc;
      if (q < 2) {
        unsigned* axw = (unsigned*)&ax;
        axw[0] = __builtin_amdgcn_perm(__float_as_uint(px0[1]),
                                       __float_as_uint(px0[0]), 0x07060302u);
        axw[1] = __builtin_amdgcn_perm(__float_as_uint(px0[3]),
                                       __float_as_uint(px0[2]), 0x07060302u);
        axw[2] = __builtin_amdgcn_perm(__float_as_uint(px1[1]),
                                       __float_as_uint(px1[0]), 0x07060302u);
        axw[3] = __builtin_amdgcn_perm(__float_as_uint(px1[3]),
                                       __float_as_uint(px1[2]), 0x07060302u);
      }

      // 3) next-step x prefetch (long latency; overlaps MFMA + pointwise).
      const int tn = last ? t : t + 1;
      if (q < 2) {
        const float* xp = xbase + ((size_t)tn * 2048 + (size_t)(2 * jm + q)) * 8;
        px0 = *(const floatx4*)xp;
        px1 = *(const floatx4*)(xp + 4);
      }

      // 4) MFMA: x-conv first (register operands, C=0) while ds_reads land.
      floatx4 acc[8];
#pragma unroll
      for (int n = 0; n < 8; ++n)
        acc[n] = __builtin_amdgcn_mfma_f32_16x16x32_bf16(ax, Bxw[n], zero4, 0, 0, 0);
#pragma unroll
      for (int n = 0; n < 8; ++n)
        acc[n] = __builtin_amdgcn_mfma_f32_16x16x32_bf16(a0h, Bwh0[n], acc[n], 0, 0, 0);
#pragma unroll
      for (int n = 0; n < 8; ++n)
        acc[n] = __builtin_amdgcn_mfma_f32_16x16x32_bf16(a1h, Bwh1[n], acc[n], 0, 0, 0);

      // 5) Pointwise LSTM. D[row = q*4+r][tile n, col f0 -> h-col 2f0+(n&1)].
      // Gate g in tiles {2g, 2g+1}: zi=acc[0+p], zf=acc[2+p], zc=acc[4+p],
      // zo=acc[6+p] give h-col 2f0+p.
      const int jw = wave * 16 + q * 4;
#pragma unroll
      for (int r = 0; r < 4; ++r) {
        float hv2[2];
#pragma unroll
        for (int p = 0; p < 2; ++p) {
          float zi = acc[0 + p][r], zf = acc[2 + p][r];
          float zc = acc[4 + p][r], zo = acc[6 + p][r];
          float ig = hsig(zi), fg = hsig(zf), og = hsig(zo);
          float cs = cst[p * 4 + r];
          float cn = __builtin_fmaf(fg, cs, ig * ftanh(zc));
          cst[p * 4 + r] = cn;
          hv2[p] = og * ftanh(cn);
        }
        if (!last) {
          unsigned pk;
          asm("v_cvt_pk_bf16_f32 %0, %1, %2"
              : "=v"(pk) : "v"(hv2[0]), "v"(hv2[1]));
          *(unsigned*)&nxtH[(jw + r) * HSTR + 2 * f0] = pk;
        } else {
          // t=49: nmt=4 -> waves 0..3; rows jw+r cover exactly [0,64).
          const int di = (j0 + jw + r) * 32 + 2 * f0;
          part = __builtin_fmaf(hv2[0], dws[di],
                 __builtin_fmaf(hv2[1], dws[di + 1], part));
        }
      }
    }
    __syncthreads();
  }

  // ---- reduce fused-dense partials (waves 4..7 hold zeros; atomics cheap)
#pragma unroll
  for (int off = 32; off > 0; off >>= 1) part += __shfl_down(part, off);
  if (lane == 0 && wave < 4) atomicAdd(&acc_out[b], part);
}

__global__ void finalize(const float* __restrict__ ws,
                         const float* __restrict__ db,
                         float* __restrict__ out) {
  int i = threadIdx.x;
  if (i < 32) out[i] = ws[i] + db[0];
}

extern "C" void kernel_launch(void* const* d_in, const int* in_sizes, int n_in,
                              void* d_out, int out_size, void* d_ws, size_t ws_size,
                              hipStream_t stream) {
  const float* x  = (const float*)d_in[0];
  const float* k  = (const float*)d_in[1];
  const float* rk = (const float*)d_in[2];
  const float* bi = (const float*)d_in[3];
  const float* dw = (const float*)d_in[4];
  const float* db = (const float*)d_in[5];
  float* ws = (float*)d_ws;
  float* out = (float*)d_out;

  hipLaunchKernelGGL(prep, dim3(1), dim3(512), 0, stream, k, rk, bi, ws);
  hipLaunchKernelGGL(convlstm_scan, dim3(512), dim3(512), 0, stream,
                     x, dw, ws);
  hipLaunchKernelGGL(finalize, dim3(1), dim3(64), 0, stream, ws, db, out);
}